// Round 4
// baseline (861.422 us; speedup 1.0000x reference)
//
#include <hip/hip_runtime.h>
#include <math.h>

#define BB 8
#define CC 256
#define HH 128
#define WW 128
#define NN (HH*WW)          // 16384
#define NBVEC 16
#define CSPLIT 16
#define CCHUNK (CC/CSPLIT)  // 16
#define NBX (NN/256)        // 64

// ---------------- workspace layout (bytes) ----------------
// score  double[B][N]           @ 0        : 1048576
// d2part float [CSPLIT][B][N]   @ 1048576  : 8388608   (fp32: halves the
//                                            32 MB/iter round-trip; 6e-8 rel
//                                            perturbation vs ~1e-5 argmax margins)
// wpart  double[NBX][B][C]      @ 9437184  : 1048576
// sumSim double[2][B]           @ 10485760 : 128
// bmaxv  double[B][NBX]         @ 10485888 : 4096
// bmaxi  int   [B][NBX]         @ 10489984 : 2048
// total ~10.5 MB

// Fused kernel: ONE pass over x per iteration. Block (nb, cz, b) owns
// c in [cz*16, cz*16+16), n in [nb*256, nb*256+256).
//   - every block redundantly reduces the 64 argmax partials -> sel
//   - gathers its own 16 rv values from x at column sel
//   - register-stages 16 x-values (16 loads in flight), LDS tile (iter>0),
//     fp64 d2 partial -> d2part[cz][b][n] as fp32
//   - pass B (iter>0): wsum partial for PREVIOUS iter's sim -> wpart[nb][b][c]
// LDS ~19.6 KB -> 8 blocks/CU = 32 waves/CU (round-3 fix, confirmed).
__global__ __launch_bounds__(256, 8)
void fused_kernel(const float* __restrict__ x,
                  float* __restrict__ out,
                  const double* __restrict__ bmaxv,
                  const int* __restrict__ bmaxi,
                  float* __restrict__ d2part,
                  double* __restrict__ wpart, int iter)
{
    const int b  = blockIdx.z;
    const int cz = blockIdx.y;
    const int nb = blockIdx.x;
    const int t  = threadIdx.x;
    const int n  = nb*256 + t;

    __shared__ float s_x[CCHUNK][257];   // stride 257: pass-B reads conflict-free
    __shared__ float s_sim[256];
    __shared__ float s_rv[CCHUNK];
    __shared__ union UScratch {
        double part[16][CCHUNK];                       // pass-B partials
        struct { double val[NBX]; int idx[NBX]; } mx;  // argmax reduce
    } s_u;

    float* out_sims   = out + (size_t)NBVEC*BB*CC;            // [NBVEC][B][N]
    float* out_selpos = out_sims + (size_t)NBVEC*BB*NN;       // [B][N]

    // ---- select index (redundant per block; first-occurrence tie-break) ----
    int sel = NN/2;
    if (iter > 0 && iter < NBVEC) {
        if (t < NBX) { s_u.mx.val[t] = bmaxv[b*NBX + t]; s_u.mx.idx[t] = bmaxi[b*NBX + t]; }
        __syncthreads();
        for (int s = NBX/2; s > 0; s >>= 1) {
            if (t < s) {
                double v2 = s_u.mx.val[t+s]; int i2 = s_u.mx.idx[t+s];
                if (v2 > s_u.mx.val[t] || (v2 == s_u.mx.val[t] && i2 < s_u.mx.idx[t])) {
                    s_u.mx.val[t] = v2; s_u.mx.idx[t] = i2;
                }
            }
            __syncthreads();
        }
        sel = s_u.mx.idx[0];   // into register before union is reused
    }

    if (iter < NBVEC) {
        if (t < CCHUNK)
            s_rv[t] = x[((size_t)b*CC + (size_t)cz*CCHUNK + t)*NN + sel];
        if (t == 0 && nb == 0 && cz == 0)
            out_selpos[(size_t)b*NN + sel] += 1.0f;
    }
    if (iter > 0)
        s_sim[t] = out_sims[(size_t)(iter-1)*BB*NN + (size_t)b*NN + n];
    __syncthreads();

    // ---- register-stage the x tile (16 independent loads = full MLP) ----
    const float* xb = x + ((size_t)b*CC + (size_t)cz*CCHUNK)*NN;
    float r[CCHUNK];
    #pragma unroll
    for (int c = 0; c < CCHUNK; ++c)
        r[c] = xb[(size_t)c*NN + n];
    if (iter > 0) {                       // LDS tile only needed by pass B
        #pragma unroll
        for (int c = 0; c < CCHUNK; ++c)
            s_x[c][t] = r[c];
    }

    // ---- pass A: d2 partial (fp64 chain, fixed c-ascending order) ----
    if (iter < NBVEC) {
        double acc = 0.0;
        #pragma unroll
        for (int c = 0; c < CCHUNK; ++c) {
            double diff = (double)r[c] - (double)s_rv[c];
            acc = fma(diff, diff, acc);
        }
        d2part[((size_t)cz*BB + b)*NN + n] = (float)acc;
    }
    __syncthreads();

    // ---- pass B: wsum partial for previous iter's sim ----
    if (iter > 0) {
        const int c = t & 15;        // 16 c's
        const int g = t >> 4;        // 16 n-groups of 16
        double w = 0.0;
        #pragma unroll
        for (int k = 0; k < 16; ++k) {
            const int nn2 = g*16 + k;
            w = fma((double)s_sim[nn2], (double)s_x[c][nn2], w);
        }
        s_u.part[g][c] = w;
        __syncthreads();
        if (t < CCHUNK) {
            double t0 = 0.0, t1 = 0.0;
            #pragma unroll
            for (int gg = 0; gg < 16; gg += 2) {     // fixed order, 2 chains
                t0 += s_u.part[gg][t];
                t1 += s_u.part[gg+1][t];
            }
            wpart[((size_t)nb*BB + b)*CC + (size_t)cz*CCHUNK + t] = t0 + t1;
        }
    }
}

// Finisher: grid (N/256, B).
//  - d2 = sum of 16 fp32 partials (fixed order, 2 chains); sim = exp(-sqrt(d2+1e-12)/20)
//  - out_sims (fp32), score update (fp64)
//  - sumSim + argmax via per-wave __shfl_down butterflies (deterministic;
//    argmax op is a semilattice -> order-independent, first-occurrence kept)
//  - block (0,b), iter>0: repr_{iter-1} finalize with 4 fixed-order chains
__global__ void finish_kernel(float* __restrict__ out,
                              double* __restrict__ score,
                              const float* __restrict__ d2part,
                              double* __restrict__ sumSim,
                              const double* __restrict__ wpart,
                              double* __restrict__ bmaxv,
                              int* __restrict__ bmaxi, int iter)
{
    const int b = blockIdx.y;
    const int t = threadIdx.x;
    const int n = blockIdx.x * 256 + t;
    const size_t si = (size_t)b*NN + n;
    const int lane = t & 63;
    const int wave = t >> 6;

    double a0 = 0.0, a1 = 0.0;
    #pragma unroll
    for (int cz = 0; cz < CSPLIT; cz += 2) {         // 16 independent loads
        a0 += (double)d2part[((size_t)cz*BB + b)*NN + n];
        a1 += (double)d2part[((size_t)(cz+1)*BB + b)*NN + n];
    }
    double d2 = a0 + a1;

    double d   = sqrt(d2 + 1e-12);
    double sim = exp(-(d / 20.0));

    float* out_sims = out + (size_t)NBVEC*BB*CC;   // [NBVEC][B][N]
    out_sims[(size_t)iter*BB*NN + si] = (float)sim;

    double sc;
    if (iter == 0) sc = 1.0 - sim;
    else           sc = (1.0 - sim) * score[si];
    score[si] = sc;

    // ---- per-wave sumSim reduce (butterfly, fixed order) ----
    double v = sim;
    #pragma unroll
    for (int off = 32; off > 0; off >>= 1) v += __shfl_down(v, off, 64);

    // ---- per-wave argmax reduce (max, lower-idx-on-tie: semilattice) ----
    double bv = sc; int bi = n;
    #pragma unroll
    for (int off = 32; off > 0; off >>= 1) {
        double ov = __shfl_down(bv, off, 64);
        int    oi = __shfl_down(bi, off, 64);
        if (ov > bv || (ov == bv && oi < bi)) { bv = ov; bi = oi; }
    }

    __shared__ double s_ws[4];
    __shared__ double s_wv[4];
    __shared__ int    s_wi[4];
    if (lane == 0) { s_ws[wave] = v; s_wv[wave] = bv; s_wi[wave] = bi; }
    __syncthreads();
    if (t == 0) {
        double tot = ((s_ws[0] + s_ws[1]) + (s_ws[2] + s_ws[3]));  // fixed order
        atomicAdd(&sumSim[(size_t)(iter & 1)*BB + b], tot);
        double cv = s_wv[0]; int ci = s_wi[0];
        #pragma unroll
        for (int w = 1; w < 4; ++w) {        // ascending wave = ascending n
            if (s_wv[w] > cv || (s_wv[w] == cv && s_wi[w] < ci)) { cv = s_wv[w]; ci = s_wi[w]; }
        }
        bmaxv[(size_t)b*NBX + blockIdx.x] = cv;
        bmaxi[(size_t)b*NBX + blockIdx.x] = ci;
    }

    // deferred repr finalize for the PREVIOUS iteration (4 fixed-order chains)
    if (iter > 0 && blockIdx.x == 0) {
        const int slotPrev = (iter-1) & 1;
        double ss = sumSim[(size_t)slotPrev*BB + b];
        if (t < CC) {
            double c0 = 0.0, c1 = 0.0, c2 = 0.0, c3 = 0.0;
            for (int nb = 0; nb < NBX; nb += 4) {
                c0 += wpart[((size_t)(nb+0)*BB + b)*CC + t];
                c1 += wpart[((size_t)(nb+1)*BB + b)*CC + t];
                c2 += wpart[((size_t)(nb+2)*BB + b)*CC + t];
                c3 += wpart[((size_t)(nb+3)*BB + b)*CC + t];
            }
            double tot = ((c0 + c1) + (c2 + c3));
            out[(size_t)(iter-1)*BB*CC + (size_t)b*CC + t] = (float)(tot / ss);
        }
        __syncthreads();
        if (t == 0) sumSim[(size_t)slotPrev*BB + b] = 0.0;
    }
}

// Final repr (iter 15): wpart from the tail fused call, sumSim slot 15&1.
__global__ void final_repr_kernel(float* __restrict__ out,
                                  const double* __restrict__ sumSim,
                                  const double* __restrict__ wpart)
{
    const int b = blockIdx.x;
    const int t = threadIdx.x;
    double ss = sumSim[(size_t)((NBVEC-1) & 1)*BB + b];
    if (t < CC) {
        double c0 = 0.0, c1 = 0.0, c2 = 0.0, c3 = 0.0;
        for (int nb = 0; nb < NBX; nb += 4) {
            c0 += wpart[((size_t)(nb+0)*BB + b)*CC + t];
            c1 += wpart[((size_t)(nb+1)*BB + b)*CC + t];
            c2 += wpart[((size_t)(nb+2)*BB + b)*CC + t];
            c3 += wpart[((size_t)(nb+3)*BB + b)*CC + t];
        }
        double tot = ((c0 + c1) + (c2 + c3));
        out[(size_t)(NBVEC-1)*BB*CC + (size_t)b*CC + t] = (float)(tot / ss);
    }
}

extern "C" void kernel_launch(void* const* d_in, const int* in_sizes, int n_in,
                              void* d_out, int out_size, void* d_ws, size_t ws_size,
                              hipStream_t stream)
{
    const float* x = (const float*)d_in[0];
    // d_in[1] (prior) is provably unused: ind at i==0 is forced to N/2 and
    // score is overwritten with (1 - sim) at i==0, discarding the prior.
    // d_in[2] (nbVec) fixed at 16 by the problem shapes.
    float* out = (float*)d_out;

    char* ws = (char*)d_ws;
    double* score  = (double*)(ws);
    float*  d2part = (float*) (ws + 1048576);
    double* wpart  = (double*)(ws + 9437184);
    double* sumSim = (double*)(ws + 10485760);
    double* bmaxv  = (double*)(ws + 10485888);
    int*    bmaxi  = (int*)   (ws + 10489984);

    // d_out/d_ws are poisoned before every launch: zero what we accumulate into.
    float* out_selpos = out + (size_t)NBVEC*BB*CC + (size_t)NBVEC*BB*NN;
    hipMemsetAsync(out_selpos, 0, (size_t)BB*NN*sizeof(float), stream);
    hipMemsetAsync(sumSim, 0, 2*BB*sizeof(double), stream);

    for (int i = 0; i <= NBVEC; ++i) {
        // F(i): sel+rv from finish(i-1)'s bmax partials, d2 for rv_i
        // (skipped at i==16), wsum for sim_{i-1} (skipped at i==0)
        fused_kernel<<<dim3(NBX, CSPLIT, BB), 256, 0, stream>>>(
            x, out, bmaxv, bmaxi, d2part, wpart, i);
        if (i < NBVEC)
            finish_kernel<<<dim3(NBX, BB), 256, 0, stream>>>(
                out, score, d2part, sumSim, wpart, bmaxv, bmaxi, i);
    }
    final_repr_kernel<<<BB, 256, 0, stream>>>(out, sumSim, wpart);
}